// Round 4
// baseline (335.216 us; speedup 1.0000x reference)
//
#include <hip/hip_runtime.h>

// RSCA fully-fused: AdaptiveAvgPool(7x7) + 4x scalar-embed MHA over B=128 axis
// + residuals, one kernel. x:[128,8192,7,7] f32, y:[128,8192].
//
// Math: out_attn = wo*(wv*X̄+bv)+bo, X̄ = softmax(q_i*k_j)-weighted mean of RAW
// kv values (Σ_j a_ij = 1 folds v's affine into the epilogue). k pre-scaled by
// log2e. LDS kv layout float4 {Kl,Kl,raw,raw} so packed fp32 ops (v_pk_fma_f32)
// consume .xy/.zw register pairs directly: inner loop per j = 2 pk_fma(arg)
// + 4 v_exp_f32 + 2 pk_fma(S1) + 2 pk_add(S0)  (~44 issue cyc/wave/j).

constexpr int B_SEQ = 128;
constexpr int N_COL = 8192;
constexpr int HWP   = 49;
constexpr int NT    = 256;
constexpr int TC    = 4;     // columns per block

typedef float v2f __attribute__((ext_vector_type(2)));

static __device__ __forceinline__ v2f pk_fma(v2f a, v2f b, v2f c) {
    v2f d;
    asm("v_pk_fma_f32 %0, %1, %2, %3" : "=v"(d) : "v"(a), "v"(b), "v"(c));
    return d;
}
static __device__ __forceinline__ v2f pk_add(v2f a, v2f b) {
    v2f d;
    asm("v_pk_add_f32 %0, %1, %2" : "=v"(d) : "v"(a), "v"(b));
    return d;
}

__global__ __launch_bounds__(NT, 5) void rsca_fused(
    const float* __restrict__ x, const float* __restrict__ y,
    const float* __restrict__ pwq, const float* __restrict__ pwk,
    const float* __restrict__ pwv, const float* __restrict__ pbq,
    const float* __restrict__ pbk, const float* __restrict__ pbv,
    const float* __restrict__ pwo, const float* __restrict__ pbo,
    float* __restrict__ out)
{
    __shared__ float4 kvxT[TC][B_SEQ];             // [c][j] {Kl,Kl,raw,raw}
    __shared__ float4 kvyT[TC][B_SEQ];
    __shared__ float  pmn[2][TC][8], pmx[2][TC][8];
    __shared__ float  klmn[2][TC], klmx[2][TC];

    const int t  = threadIdx.x;
    const int n0 = blockIdx.x * TC;

    const float wq = pwq[0], wk = pwk[0], wv = pwv[0];
    const float bq = pbq[0], bk = pbk[0], bv = pbv[0];
    const float wo = pwo[0], bo = pbo[0];
    const float L2E = 1.4426950408889634f;
    const float wkL = wk * L2E, bkL = bk * L2E;
    const float alpha = wo * wv;
    const float beta2 = 2.0f * (wo * bv + bo);

    // ---- stage y -> kvyT ----
    for (int cell = t; cell < B_SEQ * TC; cell += NT) {
        const int j = cell >> 2, c = cell & 3;
        const float fy = y[(size_t)j * N_COL + n0 + c];
        const float kl = fmaf(fy, wkL, bkL);
        kvyT[c][j] = make_float4(kl, kl, fy, fy);
    }

    // ---- pool x -> kvxT, register-direct, 13 loads in flight ----
    const int ql  = t & 3;                         // lane within quad = column c
    const int seg = t >> 2;                        // 0..63 -> row j (two passes)
    for (int pass = 0; pass < 2; ++pass) {
        const int j = pass * 64 + seg;
        const float4* __restrict__ base =
            (const float4*)(x + ((size_t)j * N_COL + n0) * (size_t)HWP);
        float4 v[13];
        #pragma unroll
        for (int k = 0; k < 12; ++k) v[k] = base[ql + 4 * k];
        v[12] = base[48];                          // tail line (floats 192..195)

        float s0 = 0.f, s1 = 0.f, s2 = 0.f, s3 = 0.f;
        s0 += v[0].x + v[0].y + v[0].z + v[0].w;
        s0 += v[1].x + v[1].y + v[1].z + v[1].w;
        s0 += v[2].x + v[2].y + v[2].z + v[2].w;
        s1 += v[4].x + v[4].y + v[4].z + v[4].w;
        s1 += v[5].x + v[5].y + v[5].z + v[5].w;
        s2 += v[7].x + v[7].y + v[7].z + v[7].w;
        s2 += v[8].x + v[8].y + v[8].z + v[8].w;
        s3 += v[10].x + v[10].y + v[10].z + v[10].w;
        s3 += v[11].x + v[11].y + v[11].z + v[11].w;
        { const float sm = v[3].x + v[3].y + v[3].z + v[3].w;     // ql+12
          const float cr = (ql == 0) ? v[3].x : 0.0f;             // float 48 -> c0
          s0 += cr; s1 += sm - cr; }
        { const float sm = v[6].x + v[6].y + v[6].z + v[6].w;     // ql+24
          const float cr = (ql == 0) ? (v[6].x + v[6].y) : 0.0f;  // 96,97 -> c1
          s1 += cr; s2 += sm - cr; }
        { const float sm = v[9].x + v[9].y + v[9].z + v[9].w;     // ql+36
          const float cr = (ql == 0) ? (v[9].x + v[9].y + v[9].z) : 0.0f;
          s2 += cr; s3 += sm - cr; }
        const float tail = v[12].x + v[12].y + v[12].z + v[12].w; // cell 3 tail

        s0 += __shfl_xor(s0, 1); s1 += __shfl_xor(s1, 1);
        s2 += __shfl_xor(s2, 1); s3 += __shfl_xor(s3, 1);
        s0 += __shfl_xor(s0, 2); s1 += __shfl_xor(s1, 2);
        s2 += __shfl_xor(s2, 2); s3 += __shfl_xor(s3, 2);
        float r = s0;
        r = (ql == 1) ? s1 : r;
        r = (ql == 2) ? s2 : r;
        r = (ql == 3) ? (s3 + tail) : r;
        const float mean = r * (1.0f / HWP);
        const float kl = fmaf(mean, wkL, bkL);
        kvxT[ql][j] = make_float4(kl, kl, mean, mean);
    }
    __syncthreads();

    // ---- per-(set,c) min/max of Kl ----
    if (t < 64) {
        const int set = t >> 5, c = (t >> 3) & 3, part = t & 7;
        float mn = 3.4e38f, mx = -3.4e38f;
        #pragma unroll
        for (int k = 0; k < 16; ++k) {
            const int j = part * 16 + k;
            const float vv = set ? kvyT[c][j].x : kvxT[c][j].x;
            mn = fminf(mn, vv);
            mx = fmaxf(mx, vv);
        }
        pmn[set][c][part] = mn;
        pmx[set][c][part] = mx;
    }
    __syncthreads();
    if (t < 8) {
        const int set = t >> 2, c = t & 3;
        float mn = 3.4e38f, mx = -3.4e38f;
        #pragma unroll
        for (int k = 0; k < 8; ++k) {
            mn = fminf(mn, pmn[set][c][k]);
            mx = fmaxf(mx, pmx[set][c][k]);
        }
        klmn[set][c] = mn;
        klmx[set][c] = mx;
    }
    __syncthreads();

    // ---- attention: thread = (query i, half ch); 2 columns each ----
    const int i  = t & (B_SEQ - 1);
    const int ch = t >> 7;
    #pragma unroll
    for (int cc = 0; cc < 2; ++cc) {
        const int c = ch * 2 + cc;                  // wave-uniform -> LDS broadcast
        const float4* __restrict__ px = kvxT[c];
        const float4* __restrict__ py = kvyT[c];
        const float xi = px[i].z;
        const float yi = py[i].z;
        const float qx = fmaf(xi, wq, bq);
        const float qy = fmaf(yi, wq, bq);
        const float nmsx = -(qx >= 0.0f ? qx * klmx[0][c] : qx * klmn[0][c]);
        const float nmcy = -(qy >= 0.0f ? qy * klmx[0][c] : qy * klmn[0][c]);
        const float nmsy = -(qy >= 0.0f ? qy * klmx[1][c] : qy * klmn[1][c]);
        const float nmcx = -(qx >= 0.0f ? qx * klmx[1][c] : qx * klmn[1][c]);

        const v2f q12  = { qx, qy };                // (self_x, cross_y) vs kx
        const v2f q34  = { qy, qx };                // (self_y, cross_x) vs ky
        const v2f nm12 = { nmsx, nmcy };
        const v2f nm34 = { nmsy, nmcx };
        v2f s0_12 = {0.f, 0.f}, s0_34 = {0.f, 0.f};
        v2f s1_12 = {0.f, 0.f}, s1_34 = {0.f, 0.f};

        for (int j0 = 0; j0 < B_SEQ; j0 += 4) {
            float4 kx4[4], ky4[4];
            #pragma unroll
            for (int jj = 0; jj < 4; ++jj) kx4[jj] = px[j0 + jj];  // ds_read_b128
            #pragma unroll
            for (int jj = 0; jj < 4; ++jj) ky4[jj] = py[j0 + jj];
            #pragma unroll
            for (int jj = 0; jj < 4; ++jj) {
                const v2f klx = { kx4[jj].x, kx4[jj].y };   // low reg pair
                const v2f rwx = { kx4[jj].z, kx4[jj].w };   // high reg pair
                const v2f kly = { ky4[jj].x, ky4[jj].y };
                const v2f rwy = { ky4[jj].z, ky4[jj].w };
                const v2f a12 = pk_fma(q12, klx, nm12);
                const v2f a34 = pk_fma(q34, kly, nm34);
                v2f e12, e34;
                e12.x = __builtin_amdgcn_exp2f(a12.x);
                e12.y = __builtin_amdgcn_exp2f(a12.y);
                e34.x = __builtin_amdgcn_exp2f(a34.x);
                e34.y = __builtin_amdgcn_exp2f(a34.y);
                s1_12 = pk_fma(e12, rwx, s1_12);
                s1_34 = pk_fma(e34, rwy, s1_34);
                s0_12 = pk_add(s0_12, e12);
                s0_34 = pk_add(s0_34, e34);
            }
        }
        // s*_12 = {self_x, cross_y}, s*_34 = {self_y, cross_x}
        const float mx_attn = s1_12.x * __builtin_amdgcn_rcpf(s0_12.x)
                            + s1_34.y * __builtin_amdgcn_rcpf(s0_34.y);
        const float my_attn = s1_34.x * __builtin_amdgcn_rcpf(s0_34.x)
                            + s1_12.y * __builtin_amdgcn_rcpf(s0_12.y);
        out[(size_t)i * (2 * N_COL) + n0 + c]         = fmaf(alpha, mx_attn, beta2 + xi);
        out[(size_t)i * (2 * N_COL) + N_COL + n0 + c] = fmaf(alpha, my_attn, beta2 + yi);
    }
}

extern "C" void kernel_launch(void* const* d_in, const int* in_sizes, int n_in,
                              void* d_out, int out_size, void* d_ws, size_t ws_size,
                              hipStream_t stream) {
    const float* x   = (const float*)d_in[0];
    const float* y   = (const float*)d_in[1];
    const float* pwq = (const float*)d_in[2];
    const float* pwk = (const float*)d_in[3];
    const float* pwv = (const float*)d_in[4];
    const float* pbq = (const float*)d_in[5];
    const float* pbk = (const float*)d_in[6];
    const float* pbv = (const float*)d_in[7];
    const float* pwo = (const float*)d_in[8];
    const float* pbo = (const float*)d_in[9];
    float* out = (float*)d_out;

    rsca_fused<<<dim3(N_COL / TC), dim3(NT), 0, stream>>>(
        x, y, pwq, pwk, pwv, pbq, pbk, pbv, pwo, pbo, out);
}

// Round 5
// 333.005 us; speedup vs baseline: 1.0066x; 1.0066x over previous
//
#include <hip/hip_runtime.h>

// RSCA fully-fused: AdaptiveAvgPool(7x7) + 4x scalar-embed MHA over B=128 axis
// + residuals, one kernel. x:[128,8192,7,7] f32, y:[128,8192].
//
// Math: out_attn = wo*(wv*X̄+bv)+bo, X̄ = softmax(q_i*k_j)-weighted mean of RAW
// kv values (Σ_j a_ij = 1 folds v's affine into the epilogue). k pre-scaled by
// log2e in LDS as float2 {Kl, raw}; inner loop per (attn,j) = fma + v_exp2 +
// fma + add. Scalar code, no inline asm (R4 lesson: asm operand copies +
// VGPR=32 straitjacket serialized both phases). launch_bounds(256,6): VGPR cap
// ~84 so pool keeps 13 float4 loads in flight and attn holds 8-j LDS chunks.

constexpr int B_SEQ = 128;
constexpr int N_COL = 8192;
constexpr int HWP   = 49;
constexpr int NT    = 256;
constexpr int TC    = 4;     // columns per block

__global__ __launch_bounds__(NT, 6) void rsca_fused(
    const float* __restrict__ x, const float* __restrict__ y,
    const float* __restrict__ pwq, const float* __restrict__ pwk,
    const float* __restrict__ pwv, const float* __restrict__ pbq,
    const float* __restrict__ pbk, const float* __restrict__ pbv,
    const float* __restrict__ pwo, const float* __restrict__ pbo,
    float* __restrict__ out)
{
    __shared__ float2 kvxT[TC][B_SEQ];             // [c][j] {Kl, raw}, j contiguous
    __shared__ float2 kvyT[TC][B_SEQ];
    __shared__ float  pmn[2][TC][8], pmx[2][TC][8];
    __shared__ float  klmn[2][TC], klmx[2][TC];

    const int t  = threadIdx.x;
    const int n0 = blockIdx.x * TC;

    const float wq = pwq[0], wk = pwk[0], wv = pwv[0];
    const float bq = pbq[0], bk = pbk[0], bv = pbv[0];
    const float wo = pwo[0], bo = pbo[0];
    const float L2E = 1.4426950408889634f;
    const float wkL = wk * L2E, bkL = bk * L2E;
    const float alpha = wo * wv;
    const float beta2 = 2.0f * (wo * bv + bo);

    // ---- stage y -> kvyT ----
    for (int cell = t; cell < B_SEQ * TC; cell += NT) {
        const int j = cell >> 2, c = cell & 3;
        const float fy = y[(size_t)j * N_COL + n0 + c];
        kvyT[c][j] = make_float2(fmaf(fy, wkL, bkL), fy);
    }

    // ---- pool x -> kvxT, register-direct, 13 loads in flight ----
    const int ql  = t & 3;                         // lane within quad = column c
    const int seg = t >> 2;                        // 0..63 -> row j (two passes)
    for (int pass = 0; pass < 2; ++pass) {
        const int j = pass * 64 + seg;
        const float4* __restrict__ base =
            (const float4*)(x + ((size_t)j * N_COL + n0) * (size_t)HWP);
        float4 v[13];
        #pragma unroll
        for (int k = 0; k < 12; ++k) v[k] = base[ql + 4 * k];
        v[12] = base[48];                          // tail line (floats 192..195)

        float s0 = 0.f, s1 = 0.f, s2 = 0.f, s3 = 0.f;
        s0 += v[0].x + v[0].y + v[0].z + v[0].w;
        s0 += v[1].x + v[1].y + v[1].z + v[1].w;
        s0 += v[2].x + v[2].y + v[2].z + v[2].w;
        s1 += v[4].x + v[4].y + v[4].z + v[4].w;
        s1 += v[5].x + v[5].y + v[5].z + v[5].w;
        s2 += v[7].x + v[7].y + v[7].z + v[7].w;
        s2 += v[8].x + v[8].y + v[8].z + v[8].w;
        s3 += v[10].x + v[10].y + v[10].z + v[10].w;
        s3 += v[11].x + v[11].y + v[11].z + v[11].w;
        { const float sm = v[3].x + v[3].y + v[3].z + v[3].w;     // ql+12
          const float cr = (ql == 0) ? v[3].x : 0.0f;             // float 48 -> c0
          s0 += cr; s1 += sm - cr; }
        { const float sm = v[6].x + v[6].y + v[6].z + v[6].w;     // ql+24
          const float cr = (ql == 0) ? (v[6].x + v[6].y) : 0.0f;  // 96,97 -> c1
          s1 += cr; s2 += sm - cr; }
        { const float sm = v[9].x + v[9].y + v[9].z + v[9].w;     // ql+36
          const float cr = (ql == 0) ? (v[9].x + v[9].y + v[9].z) : 0.0f;
          s2 += cr; s3 += sm - cr; }
        const float tail = v[12].x + v[12].y + v[12].z + v[12].w; // cell 3 tail

        s0 += __shfl_xor(s0, 1); s1 += __shfl_xor(s1, 1);
        s2 += __shfl_xor(s2, 1); s3 += __shfl_xor(s3, 1);
        s0 += __shfl_xor(s0, 2); s1 += __shfl_xor(s1, 2);
        s2 += __shfl_xor(s2, 2); s3 += __shfl_xor(s3, 2);
        float r = s0;
        r = (ql == 1) ? s1 : r;
        r = (ql == 2) ? s2 : r;
        r = (ql == 3) ? (s3 + tail) : r;
        const float mean = r * (1.0f / HWP);
        kvxT[ql][j] = make_float2(fmaf(mean, wkL, bkL), mean);
    }
    __syncthreads();

    // ---- per-(set,c) min/max of Kl ----
    if (t < 64) {
        const int set = t >> 5, c = (t >> 3) & 3, part = t & 7;
        float mn = 3.4e38f, mx = -3.4e38f;
        #pragma unroll
        for (int k = 0; k < 16; ++k) {
            const int j = part * 16 + k;
            const float vv = set ? kvyT[c][j].x : kvxT[c][j].x;
            mn = fminf(mn, vv);
            mx = fmaxf(mx, vv);
        }
        pmn[set][c][part] = mn;
        pmx[set][c][part] = mx;
    }
    __syncthreads();
    if (t < 8) {
        const int set = t >> 2, c = t & 3;
        float mn = 3.4e38f, mx = -3.4e38f;
        #pragma unroll
        for (int k = 0; k < 8; ++k) {
            mn = fminf(mn, pmn[set][c][k]);
            mx = fmaxf(mx, pmx[set][c][k]);
        }
        klmn[set][c] = mn;
        klmx[set][c] = mx;
    }
    __syncthreads();

    // ---- attention: thread = (query i, half ch); 2 columns each ----
    const int i  = t & (B_SEQ - 1);
    const int ch = t >> 7;
    #pragma unroll
    for (int cc = 0; cc < 2; ++cc) {
        const int c = ch * 2 + cc;                  // wave-uniform -> LDS broadcast
        const float2* __restrict__ px = kvxT[c];
        const float2* __restrict__ py = kvyT[c];
        const float xi = px[i].y;
        const float yi = py[i].y;
        const float qx = fmaf(xi, wq, bq);
        const float qy = fmaf(yi, wq, bq);
        const float nmsx = -(qx >= 0.0f ? qx * klmx[0][c] : qx * klmn[0][c]);
        const float nmcy = -(qy >= 0.0f ? qy * klmx[0][c] : qy * klmn[0][c]);
        const float nmsy = -(qy >= 0.0f ? qy * klmx[1][c] : qy * klmn[1][c]);
        const float nmcx = -(qx >= 0.0f ? qx * klmx[1][c] : qx * klmn[1][c]);

        float s0sx = 0.f, s1sx = 0.f, s0cy = 0.f, s1cy = 0.f;
        float s0sy = 0.f, s1sy = 0.f, s0cx = 0.f, s1cx = 0.f;
        for (int j0 = 0; j0 < B_SEQ; j0 += 8) {
            float2 kx[8], ky[8];
            #pragma unroll
            for (int jj = 0; jj < 8; ++jj) kx[jj] = px[j0 + jj];  // ds_read_b128 x4
            #pragma unroll
            for (int jj = 0; jj < 8; ++jj) ky[jj] = py[j0 + jj];
            #pragma unroll
            for (int jj = 0; jj < 8; ++jj) {
                const float e1 = __builtin_amdgcn_exp2f(fmaf(qx, kx[jj].x, nmsx));
                const float e2 = __builtin_amdgcn_exp2f(fmaf(qy, kx[jj].x, nmcy));
                const float e3 = __builtin_amdgcn_exp2f(fmaf(qy, ky[jj].x, nmsy));
                const float e4 = __builtin_amdgcn_exp2f(fmaf(qx, ky[jj].x, nmcx));
                s1sx = fmaf(e1, kx[jj].y, s1sx); s0sx += e1;
                s1cy = fmaf(e2, kx[jj].y, s1cy); s0cy += e2;
                s1sy = fmaf(e3, ky[jj].y, s1sy); s0sy += e3;
                s1cx = fmaf(e4, ky[jj].y, s1cx); s0cx += e4;
            }
        }
        const float mx_attn = s1sx * __builtin_amdgcn_rcpf(s0sx)
                            + s1cx * __builtin_amdgcn_rcpf(s0cx);
        const float my_attn = s1sy * __builtin_amdgcn_rcpf(s0sy)
                            + s1cy * __builtin_amdgcn_rcpf(s0cy);
        out[(size_t)i * (2 * N_COL) + n0 + c]         = fmaf(alpha, mx_attn, beta2 + xi);
        out[(size_t)i * (2 * N_COL) + N_COL + n0 + c] = fmaf(alpha, my_attn, beta2 + yi);
    }
}

extern "C" void kernel_launch(void* const* d_in, const int* in_sizes, int n_in,
                              void* d_out, int out_size, void* d_ws, size_t ws_size,
                              hipStream_t stream) {
    const float* x   = (const float*)d_in[0];
    const float* y   = (const float*)d_in[1];
    const float* pwq = (const float*)d_in[2];
    const float* pwk = (const float*)d_in[3];
    const float* pwv = (const float*)d_in[4];
    const float* pbq = (const float*)d_in[5];
    const float* pbk = (const float*)d_in[6];
    const float* pbv = (const float*)d_in[7];
    const float* pwo = (const float*)d_in[8];
    const float* pbo = (const float*)d_in[9];
    float* out = (float*)d_out;

    rsca_fused<<<dim3(N_COL / TC), dim3(NT), 0, stream>>>(
        x, y, pwq, pwk, pwv, pbq, pbk, pbv, pwo, pbo, out);
}